// Round 5
// baseline (217.057 us; speedup 1.0000x reference)
//
#include <hip/hip_runtime.h>
#include <hip/hip_cooperative_groups.h>

namespace cg = cooperative_groups;

#define OUTN 400
#define THRESH 0.7f
#define BB 32
#define HH 512
#define WW 512
#define CC 3
#define BIGI 0x7FFFFFFF

#define GRID_BLKS 1024
#define CHUNKS_PB 32              // chunks per batch (1024 tasks total)
#define ROWS_PC   (HH / CHUNKS_PB)   // 16 rows per chunk
#define TILES     (BB * OUTN * OUTN / 256)   // 20000
#define TILES_PB  (OUTN * OUTN / 256)        // 625 (exact)

__global__ void __launch_bounds__(256, 4) fused_kernel(
        const float* __restrict__ img,
        const float* __restrict__ tensor,
        float* __restrict__ out,
        int4* __restrict__ part,      // 1024 entries
        int4* __restrict__ finals) {  // 32 entries
    cg::grid_group grid = cg::this_grid();

    // ---------------- Phase A: per-(batch,chunk) partial bounds ----------------
    {
        const int task  = blockIdx.x;            // 0..1023
        const int b     = task >> 5;             // /32
        const int chunk = task & 31;
        const int f4_per_row = WW / 4;           // 128

        const float4* base = (const float4*)(tensor + (size_t)b * HH * WW
                                                    + (size_t)chunk * ROWS_PC * WW);

        int minR = BIGI, maxR = -1, minC = BIGI, maxC = -1;

        #pragma unroll
        for (int it = 0; it < (ROWS_PC * f4_per_row) / 256; ++it) {   // 8 iters
            int p = threadIdx.x + it * 256;
            float4 v = base[p];
            int row  = p >> 7;                 // /128, chunk-relative
            int col0 = (p & 127) * 4;
            bool m0 = v.x > THRESH, m1 = v.y > THRESH, m2 = v.z > THRESH, m3 = v.w > THRESH;
            if (m0 | m1 | m2 | m3) {
                minR = min(minR, row);
                maxR = max(maxR, row);
                if (m0) { minC = min(minC, col0    ); maxC = max(maxC, col0    ); }
                if (m1) { minC = min(minC, col0 + 1); maxC = max(maxC, col0 + 1); }
                if (m2) { minC = min(minC, col0 + 2); maxC = max(maxC, col0 + 2); }
                if (m3) { minC = min(minC, col0 + 3); maxC = max(maxC, col0 + 3); }
            }
        }

        #pragma unroll
        for (int off = 32; off > 0; off >>= 1) {
            minR = min(minR, __shfl_down(minR, off));
            maxR = max(maxR, __shfl_down(maxR, off));
            minC = min(minC, __shfl_down(minC, off));
            maxC = max(maxC, __shfl_down(maxC, off));
        }

        __shared__ int s[4];
        if (threadIdx.x == 0) { s[0] = BIGI; s[1] = -1; s[2] = BIGI; s[3] = -1; }
        __syncthreads();
        if ((threadIdx.x & 63) == 0) {
            atomicMin(&s[0], minR); atomicMax(&s[1], maxR);
            atomicMin(&s[2], minC); atomicMax(&s[3], maxC);
        }
        __syncthreads();
        if (threadIdx.x == 0) {
            int4 r;
            if (s[1] >= 0) {
                r.x = s[0] + chunk * ROWS_PC;
                r.y = s[1] + chunk * ROWS_PC;
                r.z = s[2];
                r.w = s[3];
            } else {
                r.x = BIGI; r.y = -1; r.z = BIGI; r.w = -1;
            }
            part[task] = r;
        }
        __threadfence();
    }

    grid.sync();

    // ---------------- Phase A2: fold 32 partials -> finals[b] ----------------
    if (blockIdx.x < BB && threadIdx.x < 64) {
        const int b = blockIdx.x;
        int4 p = part[b * CHUNKS_PB + (threadIdx.x & 31)];
        #pragma unroll
        for (int off = 1; off < 32; off <<= 1) {
            p.x = min(p.x, __shfl_xor(p.x, off));
            p.y = max(p.y, __shfl_xor(p.y, off));
            p.z = min(p.z, __shfl_xor(p.z, off));
            p.w = max(p.w, __shfl_xor(p.w, off));
        }
        if (threadIdx.x == 0) {
            finals[b] = p;
            __threadfence();
        }
    }

    grid.sync();

    // ---------------- Phase B: grid-stride resize ----------------
    for (int tile = blockIdx.x; tile < TILES; tile += GRID_BLKS) {
        const int b   = tile / TILES_PB;          // tile-uniform (625 tiles/batch exact)
        const int rem = tile - b * TILES_PB;
        const int pix = rem * 256 + threadIdx.x;  // 0..159999 within batch

        int4 f = finals[b];
        int minR = f.x, maxR = f.y, minC = f.z, maxC = f.w;
        if (maxR < 0) { minR = 0; maxR = HH - 1; }   // all-false mask => [0, n-1]
        if (maxC < 0) { minC = 0; maxC = WW - 1; }

        const int ocol = pix % OUTN;
        const int orow = pix / OUTN;

        // rows (matches _axis_coords exactly)
        float sizeR = (float)(maxR - minR);
        float srcR  = ((float)orow + 0.5f) * sizeR / (float)OUTN - 0.5f;
        srcR = fminf(fmaxf(srcR, 0.0f), fmaxf(sizeR - 1.0f, 0.0f));
        int   i0 = (int)floorf(srcR);
        int   i1 = min(i0 + 1, max(maxR - minR - 1, 0));
        float wr = srcR - (float)i0;
        int r0 = minR + i0, r1 = minR + i1;

        // cols
        float sizeC = (float)(maxC - minC);
        float srcC  = ((float)ocol + 0.5f) * sizeC / (float)OUTN - 0.5f;
        srcC = fminf(fmaxf(srcC, 0.0f), fmaxf(sizeC - 1.0f, 0.0f));
        int   j0 = (int)floorf(srcC);
        int   j1 = min(j0 + 1, max(maxC - minC - 1, 0));
        float wc = srcC - (float)j0;
        int c0 = minC + j0, c1 = minC + j1;

        const float* ib  = img + (size_t)b * HH * WW * CC;
        const float* p00 = ib + ((size_t)r0 * WW + c0) * CC;
        const float* p01 = ib + ((size_t)r0 * WW + c1) * CC;
        const float* p10 = ib + ((size_t)r1 * WW + c0) * CC;
        const float* p11 = ib + ((size_t)r1 * WW + c1) * CC;

        float* o = out + ((size_t)b * OUTN * OUTN + pix) * CC;
        #pragma unroll
        for (int ch = 0; ch < CC; ++ch) {
            float a00 = p00[ch], a01 = p01[ch], a10 = p10[ch], a11 = p11[ch];
            float top = a00 * (1.0f - wc) + a01 * wc;
            float bot = a10 * (1.0f - wc) + a11 * wc;
            o[ch] = top * (1.0f - wr) + bot * wr;
        }
    }
}

extern "C" void kernel_launch(void* const* d_in, const int* in_sizes, int n_in,
                              void* d_out, int out_size, void* d_ws, size_t ws_size,
                              hipStream_t stream) {
    const float* image  = (const float*)d_in[0];
    const float* tensor = (const float*)d_in[1];
    float* out    = (float*)d_out;
    int4*  part   = (int4*)d_ws;            // 1024 * 16 B
    int4*  finals = part + GRID_BLKS;       // 32 * 16 B

    void* args[] = { (void*)&image, (void*)&tensor, (void*)&out,
                     (void*)&part, (void*)&finals };
    hipLaunchCooperativeKernel((void*)fused_kernel, dim3(GRID_BLKS), dim3(256),
                               args, 0, stream);
}

// Round 6
// 42.932 us; speedup vs baseline: 5.0559x; 5.0559x over previous
//
#include <hip/hip_runtime.h>

#define OUTN 400
#define THRESH 0.7f
#define BB 32
#define HH 512
#define WW 512
#define CC 3
#define BIGI 0x7FFFFFFF

#define CHUNKS_PB 32                    // chunks per batch
#define ROWS_PC   (HH / CHUNKS_PB)      // 16 rows per chunk
#define TILES_PB  (OUTN * OUTN / 256)   // 625 tiles (256 px) per batch, exact

// Per-(batch,chunk) partial bounds, plain stores, no init / no global atomics.
// part[b*32+chunk] = {minR, maxR, minC, maxC} in GLOBAL row coords;
// empty chunk => {BIGI, -1, BIGI, -1}.
__global__ void __launch_bounds__(256) bounds_part_kernel(
        const float* __restrict__ tensor,
        int4* __restrict__ part) {
    const int task  = blockIdx.x;            // 0..1023
    const int b     = task >> 5;
    const int chunk = task & 31;

    const float4* base = (const float4*)(tensor + (size_t)b * HH * WW
                                                + (size_t)chunk * ROWS_PC * WW);

    int minR = BIGI, maxR = -1, minC = BIGI, maxC = -1;

    // 2048 float4 per chunk, 256 threads, 8 fully-unrolled iterations
    #pragma unroll
    for (int it = 0; it < 8; ++it) {
        int p = threadIdx.x + it * 256;
        float4 v = base[p];
        int row  = p >> 7;                 // /128 float4 per row, chunk-relative
        int col0 = (p & 127) * 4;
        bool m0 = v.x > THRESH, m1 = v.y > THRESH, m2 = v.z > THRESH, m3 = v.w > THRESH;
        if (m0 | m1 | m2 | m3) {
            minR = min(minR, row);
            maxR = max(maxR, row);
            if (m0) { minC = min(minC, col0    ); maxC = max(maxC, col0    ); }
            if (m1) { minC = min(minC, col0 + 1); maxC = max(maxC, col0 + 1); }
            if (m2) { minC = min(minC, col0 + 2); maxC = max(maxC, col0 + 2); }
            if (m3) { minC = min(minC, col0 + 3); maxC = max(maxC, col0 + 3); }
        }
    }

    #pragma unroll
    for (int off = 32; off > 0; off >>= 1) {
        minR = min(minR, __shfl_down(minR, off));
        maxR = max(maxR, __shfl_down(maxR, off));
        minC = min(minC, __shfl_down(minC, off));
        maxC = max(maxC, __shfl_down(maxC, off));
    }

    __shared__ int s[4];
    if (threadIdx.x == 0) { s[0] = BIGI; s[1] = -1; s[2] = BIGI; s[3] = -1; }
    __syncthreads();
    if ((threadIdx.x & 63) == 0) {
        atomicMin(&s[0], minR); atomicMax(&s[1], maxR);
        atomicMin(&s[2], minC); atomicMax(&s[3], maxC);
    }
    __syncthreads();
    if (threadIdx.x == 0) {
        int4 r;
        if (s[1] >= 0) {
            r.x = s[0] + chunk * ROWS_PC;
            r.y = s[1] + chunk * ROWS_PC;
            r.z = s[2];
            r.w = s[3];
        } else {
            r.x = BIGI; r.y = -1; r.z = BIGI; r.w = -1;
        }
        part[task] = r;
    }
}

__device__ inline int4 fold_bounds(const int4* __restrict__ part, int b, int lane) {
    int4 p = part[b * CHUNKS_PB + (lane & 31)];
    #pragma unroll
    for (int off = 1; off < 32; off <<= 1) {
        p.x = min(p.x, __shfl_xor(p.x, off));
        p.y = max(p.y, __shfl_xor(p.y, off));
        p.z = min(p.z, __shfl_xor(p.z, off));
        p.w = max(p.w, __shfl_xor(p.w, off));
    }
    if (p.y < 0) { p.x = 0; p.y = HH - 1; }   // all-false mask => [0, n-1]
    if (p.w < 0) { p.z = 0; p.w = WW - 1; }
    return p;
}

// Two 256-pixel tiles per block (tile index block-uniform), 2 px per thread for MLP.
__global__ void __launch_bounds__(256) resize_kernel(
        const float* __restrict__ img,
        const int4* __restrict__ part,
        float* __restrict__ out) {
    const int lane  = threadIdx.x & 63;
    const int tile0 = blockIdx.x * 2;
    const int tile1 = tile0 + 1;
    const int b0 = tile0 / TILES_PB;
    const int b1 = tile1 / TILES_PB;

    int4 f0 = fold_bounds(part, b0, lane);
    int4 f1 = (b1 == b0) ? f0 : fold_bounds(part, b1, lane);

    float res[2][12];
    size_t obase[2];

    #pragma unroll
    for (int q = 0; q < 2; ++q) {
        const int tile = q ? tile1 : tile0;
        const int b    = q ? b1 : b0;
        const int4 f   = q ? f1 : f0;
        const int pix  = (tile - b * TILES_PB) * 256 + threadIdx.x;
        const int ocol = pix % OUTN;
        const int orow = pix / OUTN;

        const int minR = f.x, maxR = f.y, minC = f.z, maxC = f.w;

        float sizeR = (float)(maxR - minR);
        float srcR  = ((float)orow + 0.5f) * sizeR / (float)OUTN - 0.5f;
        srcR = fminf(fmaxf(srcR, 0.0f), fmaxf(sizeR - 1.0f, 0.0f));
        int   i0 = (int)floorf(srcR);
        int   i1 = min(i0 + 1, max(maxR - minR - 1, 0));
        float wr = srcR - (float)i0;
        int r0 = minR + i0, r1 = minR + i1;

        float sizeC = (float)(maxC - minC);
        float srcC  = ((float)ocol + 0.5f) * sizeC / (float)OUTN - 0.5f;
        srcC = fminf(fmaxf(srcC, 0.0f), fmaxf(sizeC - 1.0f, 0.0f));
        int   j0 = (int)floorf(srcC);
        int   j1 = min(j0 + 1, max(maxC - minC - 1, 0));
        float wc = srcC - (float)j0;
        int c0 = minC + j0, c1 = minC + j1;

        const float* ib  = img + (size_t)b * HH * WW * CC;
        const float* p00 = ib + ((size_t)r0 * WW + c0) * CC;
        const float* p01 = ib + ((size_t)r0 * WW + c1) * CC;
        const float* p10 = ib + ((size_t)r1 * WW + c0) * CC;
        const float* p11 = ib + ((size_t)r1 * WW + c1) * CC;

        float omc = 1.0f - wc, omr = 1.0f - wr;
        #pragma unroll
        for (int ch = 0; ch < CC; ++ch) {
            float a00 = p00[ch], a01 = p01[ch], a10 = p10[ch], a11 = p11[ch];
            float top = a00 * omc + a01 * wc;
            float bot = a10 * omc + a11 * wc;
            res[q][ch] = top * omr + bot * wr;
        }
        obase[q] = ((size_t)b * OUTN * OUTN + (size_t)pix) * CC;
    }

    #pragma unroll
    for (int q = 0; q < 2; ++q) {
        float* o = out + obase[q];
        __builtin_nontemporal_store(res[q][0], o + 0);
        __builtin_nontemporal_store(res[q][1], o + 1);
        __builtin_nontemporal_store(res[q][2], o + 2);
    }
}

extern "C" void kernel_launch(void* const* d_in, const int* in_sizes, int n_in,
                              void* d_out, int out_size, void* d_ws, size_t ws_size,
                              hipStream_t stream) {
    const float* image  = (const float*)d_in[0];
    const float* tensor = (const float*)d_in[1];
    float* out  = (float*)d_out;
    int4*  part = (int4*)d_ws;   // 1024 * 16 B = 16 KB

    hipLaunchKernelGGL(bounds_part_kernel, dim3(BB * CHUNKS_PB), dim3(256), 0, stream,
                       tensor, part);

    int tiles  = BB * OUTN * OUTN / 256;      // 20000
    hipLaunchKernelGGL(resize_kernel, dim3(tiles / 2), dim3(256), 0, stream,
                       image, part, out);
}